// Round 3
// baseline (179.608 us; speedup 1.0000x reference)
//
#include <hip/hip_runtime.h>

// NonMaxSuppression (Canny thinning), H=W=4096, fp32.
//
// R6: R5 structure (2 rows/thread, direct per-lane halo loads, nt stores)
// with two cache-policy changes:
// (1) orient loads are PLAIN (was nontemporal): working set 192 MB < 256 MB
//     L3, so orient is retainable across dispatches -- nt was forcing a
//     64 MB HBM re-fetch every dispatch (R5 FETCH=101MB vs R4's plain-load
//     87.6MB at higher demand).
// (2) XCD-chunk blockIdx swizzle: each XCD gets a contiguous 512-row band,
//     so vertical mag halo re-reads are XCD-local L2 hits instead of
//     cross-XCD L3 round trips (latency cut, helps the latency-bound regime).

constexpr int H = 4096;
constexpr int W = 4096;

typedef float v4f __attribute__((ext_vector_type(4)));

// Per-row NMS over 4 pixels. u6/c6/d6 = 6-wide (x0-1 .. x0+4) slices of rows
// y-1, y, y+1. Direction table: (dy,dx) by c =
// 0:(0,1) 1:(1,1) 2:(1,0) 3:(1,-1) 4:(0,-1) 5:(-1,-1) 6:(-1,0) 7:(-1,1)
__device__ __forceinline__ v4f nms_row(const float u6[6], const float c6[6],
                                       const float d6[6], v4f m4, v4f o4,
                                       const float b[8])
{
    v4f res;
    const float m[4] = {m4.x, m4.y, m4.z, m4.w};
    const float o[4] = {o4.x, o4.y, o4.z, o4.w};
    float r[4];
    #pragma unroll
    for (int k = 0; k < 4; ++k) {
        // orient is an exact non-negative multiple of 45 in [0,315];
        // fma + trunc rounds the 1-ulp reciprocal error away. c in [0,7].
        const int c = (int)(o[k] * 0.0222222222f + 0.5f);
        const bool b0 = (c & 1), b1 = (c & 2), b2 = (c & 4);

        // t_i = n_i - bias_i  (pos = m - t[c], neg = m - t[c^4])
        const float t0 = c6[k + 2] - b[0];
        const float t1 = d6[k + 2] - b[1];
        const float t2 = d6[k + 1] - b[2];
        const float t3 = d6[k]     - b[3];
        const float t4 = c6[k]     - b[4];
        const float t5 = u6[k]     - b[5];
        const float t6 = u6[k + 1] - b[6];
        const float t7 = u6[k + 2] - b[7];

        // 3-level select tree; levels 1-2 shared, level 3 flips on bit2
        const float s01 = b0 ? t1 : t0;
        const float s23 = b0 ? t3 : t2;
        const float s45 = b0 ? t5 : t4;
        const float s67 = b0 ? t7 : t6;
        const float lo  = b1 ? s23 : s01;   // t[(0..3) sel by bits 0,1]
        const float hi  = b1 ? s67 : s45;   // t[(4..7) sel by bits 0,1]
        const float tp  = b2 ? hi : lo;     // t[c]
        const float tn  = b2 ? lo : hi;     // t[c^4]

        // min(m-tp, m-tn) > 0  <=>  m > max(tp, tn)
        r[k] = (m[k] > fmaxf(tp, tn)) ? m[k] : 0.0f;
    }
    res.x = r[0]; res.y = r[1]; res.z = r[2]; res.w = r[3];
    return res;
}

__global__ __launch_bounds__(256) void nms_kernel(
    const float* __restrict__ mag,
    const float* __restrict__ orient,
    const float* __restrict__ bias,
    float* __restrict__ out)
{
    // XCD-chunk swizzle: hardware runs block b on XCD b%8 (round-robin);
    // remap so XCD k executes the contiguous work band [k*nwg/8, (k+1)*nwg/8).
    // nwg = 8192, divisible by 8 -> bijective.
    const int bid = blockIdx.x;
    const int cpx = gridDim.x >> 3;                 // chunks per XCD
    const int wg  = (bid & 7) * cpx + (bid >> 3);

    const int tid  = wg * blockDim.x + threadIdx.x;
    const int ty   = tid >> 10;          // 1024 quads per row-pair
    const int xq   = tid & 1023;
    const int x0   = xq << 2;
    const int y0   = ty << 1;
    const long base0 = ((long)y0 << 12) + x0;   // row y0
    const long base1 = base0 + W;               // row y0+1

    // 4 mag rows (y0-1, y0, y0+1, y0+2); row guards are wave-uniform
    const bool has_up = (y0 > 0);
    const bool has_dn = (y0 + 2 < H);
    const v4f r0 = *reinterpret_cast<const v4f*>(mag + base0);
    const v4f r1 = *reinterpret_cast<const v4f*>(mag + base1);
    v4f uu = {0.f, 0.f, 0.f, 0.f};
    v4f dd = {0.f, 0.f, 0.f, 0.f};
    if (has_up) uu = *reinterpret_cast<const v4f*>(mag + base0 - W);
    if (has_dn) dd = *reinterpret_cast<const v4f*>(mag + base1 + W);

    // orient: plain cacheable loads -- L3 retains it across dispatches
    const v4f o0 = *reinterpret_cast<const v4f*>(orient + base0);
    const v4f o1 = *reinterpret_cast<const v4f*>(orient + base1);

    // Column halo: per-lane direct neighbor loads (branchless, clamped at
    // the image edge and zeroed by cndmask). These hit the L1 lines the
    // adjacent lanes' float4 loads fetched -- no extra HBM traffic, no DS
    // pipe, no exec-mask divergence.
    const bool has_l = (x0 > 0);
    const bool has_r = (x0 + 4 < W);
    const long laddr = has_l ? (base0 - 1) : base0;       // in-bounds clamp
    const long raddr = has_r ? (base0 + 4) : (base0 + 3); // in-bounds clamp

    float l0 = mag[laddr];
    float l1 = mag[laddr + W];
    float q0 = mag[raddr];
    float q1 = mag[raddr + W];
    float lU = 0.f, rU = 0.f, lD = 0.f, rD = 0.f;
    if (has_up) { lU = mag[laddr - W]; rU = mag[raddr - W]; }
    if (has_dn) { lD = mag[laddr + 2L * W]; rD = mag[raddr + 2L * W]; }

    l0 = has_l ? l0 : 0.f;
    l1 = has_l ? l1 : 0.f;
    lU = has_l ? lU : 0.f;
    lD = has_l ? lD : 0.f;
    q0 = has_r ? q0 : 0.f;
    q1 = has_r ? q1 : 0.f;
    rU = has_r ? rU : 0.f;
    rD = has_r ? rD : 0.f;

    const float U6[6] = {lU, uu.x, uu.y, uu.z, uu.w, rU};
    const float C0[6] = {l0, r0.x, r0.y, r0.z, r0.w, q0};
    const float C1[6] = {l1, r1.x, r1.y, r1.z, r1.w, q1};
    const float D6[6] = {lD, dd.x, dd.y, dd.z, dd.w, rD};

    float b[8];
    #pragma unroll
    for (int i = 0; i < 8; ++i) b[i] = bias[i];

    const v4f res0 = nms_row(U6, C0, C1, r0, o0, b);  // row y0
    const v4f res1 = nms_row(C0, C1, D6, r1, o1, b);  // row y0+1

    __builtin_nontemporal_store(res0, reinterpret_cast<v4f*>(out + base0));
    __builtin_nontemporal_store(res1, reinterpret_cast<v4f*>(out + base1));
}

extern "C" void kernel_launch(void* const* d_in, const int* in_sizes, int n_in,
                              void* d_out, int out_size, void* d_ws, size_t ws_size,
                              hipStream_t stream) {
    const float* mag    = (const float*)d_in[0];   // [1,1,H,W]
    const float* orient = (const float*)d_in[1];   // [1,1,H,W]
    // d_in[2] = weight [8,1,3,3] -- fixed directional filters, hardcoded
    const float* bias   = (const float*)d_in[3];   // [8]
    float* out = (float*)d_out;                    // [1,1,H,W]

    const int total = (H / 2) * (W / 4);           // one thread per 2x4 pixels
    dim3 block(256);
    dim3 grid(total / 256);
    hipLaunchKernelGGL(nms_kernel, grid, block, 0, stream,
                       mag, orient, bias, out);
}

// Round 4
// 169.323 us; speedup vs baseline: 1.0607x; 1.0607x over previous
//
#include <hip/hip_runtime.h>

// NonMaxSuppression (Canny thinning), H=W=4096, fp32.
//
// R7: persistent chained pipeline. Ladder evidence: R3/R5 (one-shot 2-row
// threads, nt orient, nt stores) = 49us; R4/R6 (plain orient) = 63-66us ->
// nt orient is right, and the kernel is latency/convoy-bound (R6 moved
// FEWER HBM bytes SLOWER). One-shot blocks issue all loads at dispatch,
// wait together, compute together, die (4 dispatch generations) -- the
// memory pipes idle between bursts. Fix: 2048 resident blocks, each thread
// sweeps 8 rows as 4 chained 2-row tiles; the next tile's batch (2 mag rows
// + 2 orient rows + 4 halo dwords) is issued BEFORE computing the current
// tile, so one batch is always in flight per wave (counted vmcnt, no
// convoy, no redispatch).

constexpr int H = 4096;
constexpr int W = 4096;

typedef float v4f __attribute__((ext_vector_type(4)));

// Per-row NMS over 4 pixels. u6/c6/d6 = 6-wide (x0-1 .. x0+4) slices of rows
// y-1, y, y+1. Direction table: (dy,dx) by c =
// 0:(0,1) 1:(1,1) 2:(1,0) 3:(1,-1) 4:(0,-1) 5:(-1,-1) 6:(-1,0) 7:(-1,1)
__device__ __forceinline__ v4f nms_row(const float u6[6], const float c6[6],
                                       const float d6[6], v4f m4, v4f o4,
                                       const float b[8])
{
    v4f res;
    const float m[4] = {m4.x, m4.y, m4.z, m4.w};
    const float o[4] = {o4.x, o4.y, o4.z, o4.w};
    float r[4];
    #pragma unroll
    for (int k = 0; k < 4; ++k) {
        // orient is an exact non-negative multiple of 45 in [0,315];
        // fma + trunc rounds the 1-ulp reciprocal error away. c in [0,7].
        const int c = (int)(o[k] * 0.0222222222f + 0.5f);
        const bool b0 = (c & 1), b1 = (c & 2), b2 = (c & 4);

        // t_i = n_i - bias_i  (pos = m - t[c], neg = m - t[c^4])
        const float t0 = c6[k + 2] - b[0];
        const float t1 = d6[k + 2] - b[1];
        const float t2 = d6[k + 1] - b[2];
        const float t3 = d6[k]     - b[3];
        const float t4 = c6[k]     - b[4];
        const float t5 = u6[k]     - b[5];
        const float t6 = u6[k + 1] - b[6];
        const float t7 = u6[k + 2] - b[7];

        // 3-level select tree; levels 1-2 shared, level 3 flips on bit2
        const float s01 = b0 ? t1 : t0;
        const float s23 = b0 ? t3 : t2;
        const float s45 = b0 ? t5 : t4;
        const float s67 = b0 ? t7 : t6;
        const float lo  = b1 ? s23 : s01;   // t[(0..3) sel by bits 0,1]
        const float hi  = b1 ? s67 : s45;   // t[(4..7) sel by bits 0,1]
        const float tp  = b2 ? hi : lo;     // t[c]
        const float tn  = b2 ? lo : hi;     // t[c^4]

        // min(m-tp, m-tn) > 0  <=>  m > max(tp, tn)
        r[k] = (m[k] > fmaxf(tp, tn)) ? m[k] : 0.0f;
    }
    res.x = r[0]; res.y = r[1]; res.z = r[2]; res.w = r[3];
    return res;
}

// Load mag row (center v4f + clamped/zeroed left & right halo dwords)
#define MAGROW(i, dy) do {                                          \
    const long rb_ = base + (long)(dy) * W;                         \
    M[i] = *reinterpret_cast<const v4f*>(mag + rb_);                \
    const float lv_ = mag[rb_ + loff];                              \
    const float rv_ = mag[rb_ + roff];                              \
    L[i] = has_l ? lv_ : 0.f;                                       \
    Q[i] = has_r ? rv_ : 0.f;                                       \
} while (0)

__global__ __launch_bounds__(256) void nms_kernel(
    const float* __restrict__ mag,
    const float* __restrict__ orient,
    const float* __restrict__ bias,
    float* __restrict__ out)
{
    const int tid = blockIdx.x * blockDim.x + threadIdx.x;
    const int ty  = tid >> 10;           // 512 groups of 8 rows
    const int xq  = tid & 1023;
    const int x0  = xq << 2;
    const int y0  = ty << 3;
    const long base = ((long)y0 << 12) + x0;

    const bool has_l = (x0 > 0);
    const bool has_r = (x0 + 4 < W);
    const long loff  = has_l ? -1L : 0L;     // clamped (value zeroed below)
    const long roff  = has_r ? 4L : 3L;

    // M[i]/L[i]/Q[i]: mag row y0-1+i. O[i]: orient row y0+i.
    v4f M[10]; float L[10], Q[10]; v4f O[8];

    // --- prologue: tile-0 window (mag rows y0-1..y0+2, orient y0..y0+1) ---
    if (y0 > 0) {                      // wave-uniform
        MAGROW(0, -1);
    } else {
        M[0] = v4f{0.f, 0.f, 0.f, 0.f}; L[0] = 0.f; Q[0] = 0.f;
    }
    MAGROW(1, 0);
    MAGROW(2, 1);
    MAGROW(3, 2);                      // y0+2 <= 4090, always in range
    O[0] = __builtin_nontemporal_load(reinterpret_cast<const v4f*>(orient + base));
    O[1] = __builtin_nontemporal_load(reinterpret_cast<const v4f*>(orient + base + (long)W));

    float b[8];
    #pragma unroll
    for (int i = 0; i < 8; ++i) b[i] = bias[i];

    const bool dn_ok = (y0 + 8 < H);   // validity of row y0+8 (M[9]); wave-uniform

    #pragma unroll
    for (int t = 0; t < 4; ++t) {
        // --- prefetch next tile's batch (issued before this tile's compute) ---
        if (t < 3) {
            MAGROW(2 * t + 4, 2 * t + 3);            // rows <= y0+7: always valid
            if (2 * t + 5 < 9 || dn_ok) {            // only M[9] (row y0+8) can be OOB
                MAGROW(2 * t + 5, 2 * t + 4);
            } else {
                M[9] = v4f{0.f, 0.f, 0.f, 0.f}; L[9] = 0.f; Q[9] = 0.f;
            }
            O[2 * t + 2] = __builtin_nontemporal_load(
                reinterpret_cast<const v4f*>(orient + base + (long)(2 * t + 2) * W));
            O[2 * t + 3] = __builtin_nontemporal_load(
                reinterpret_cast<const v4f*>(orient + base + (long)(2 * t + 3) * W));
        }

        // --- compute tile t: output rows y0+2t, y0+2t+1 (window idx 2t..2t+3) ---
        const int w0 = 2 * t, w1 = 2 * t + 1, w2 = 2 * t + 2, w3 = 2 * t + 3;
        const float A6[6] = {L[w0], M[w0].x, M[w0].y, M[w0].z, M[w0].w, Q[w0]};
        const float B6[6] = {L[w1], M[w1].x, M[w1].y, M[w1].z, M[w1].w, Q[w1]};
        const float C6[6] = {L[w2], M[w2].x, M[w2].y, M[w2].z, M[w2].w, Q[w2]};
        const float D6[6] = {L[w3], M[w3].x, M[w3].y, M[w3].z, M[w3].w, Q[w3]};

        const v4f ra = nms_row(A6, B6, C6, M[w1], O[2 * t],     b);
        const v4f rb = nms_row(B6, C6, D6, M[w2], O[2 * t + 1], b);

        __builtin_nontemporal_store(ra,
            reinterpret_cast<v4f*>(out + base + (long)(2 * t) * W));
        __builtin_nontemporal_store(rb,
            reinterpret_cast<v4f*>(out + base + (long)(2 * t + 1) * W));
    }
}

extern "C" void kernel_launch(void* const* d_in, const int* in_sizes, int n_in,
                              void* d_out, int out_size, void* d_ws, size_t ws_size,
                              hipStream_t stream) {
    const float* mag    = (const float*)d_in[0];   // [1,1,H,W]
    const float* orient = (const float*)d_in[1];   // [1,1,H,W]
    // d_in[2] = weight [8,1,3,3] -- fixed directional filters, hardcoded
    const float* bias   = (const float*)d_in[3];   // [8]
    float* out = (float*)d_out;                    // [1,1,H,W]

    const int total = (H / 8) * (W / 4);           // one thread per 8x4 pixels
    dim3 block(256);
    dim3 grid(total / 256);                        // 2048 blocks: one resident wave-front
    hipLaunchKernelGGL(nms_kernel, grid, block, 0, stream,
                       mag, orient, bias, out);
}